// Round 13
// baseline (147.634 us; speedup 1.0000x reference)
//
#include <hip/hip_runtime.h>

// TinyRecursiveModel fused kernel, v13.
// = v12 (107us champion) with ALL SIX weight matrices (W_vo l0/l1, W1 l0/l1,
//   W2 l0/l1) hoisted into VGPR fragments. __launch_bounds__(256,1) lifts the
//   compiler's 128-reg cap (hipcc models 256/SIMD pool; HW has 512 -> 2
//   waves/SIMD still resident at <=256 regs). The recurrence now touches NO
//   LDS at all (no ds_read waits, no bank conflicts, no barrier).

using f16x8 = __attribute__((ext_vector_type(8))) _Float16;
using f32x4 = __attribute__((ext_vector_type(4))) float;

#define DI __device__ __forceinline__

namespace {

constexpr float EPS = 1e-5f;

DI float rsq(float x) {
#if __has_builtin(__builtin_amdgcn_rsqf)
  return __builtin_amdgcn_rsqf(x);
#else
  float r;
  asm("v_rsq_f32 %0, %1" : "=v"(r) : "v"(x));
  return r;
#endif
}

DI unsigned pkrtz(float a, float b) {  // two f32 -> packed f16 pair (RTZ)
#if __has_builtin(__builtin_amdgcn_cvt_pkrtz)
  return __builtin_bit_cast(unsigned, __builtin_amdgcn_cvt_pkrtz(a, b));
#else
  unsigned r;
  asm("v_cvt_pkrtz_f16_f32 %0, %1, %2" : "=v"(r) : "v"(a), "v"(b));
  return r;
#endif
}

DI f16x8 cvt8h(f32x4 a, f32x4 b) {  // RNE (weight/input staging)
  f16x8 r;
  r[0] = (_Float16)a[0]; r[1] = (_Float16)a[1];
  r[2] = (_Float16)a[2]; r[3] = (_Float16)a[3];
  r[4] = (_Float16)b[0]; r[5] = (_Float16)b[1];
  r[6] = (_Float16)b[2]; r[7] = (_Float16)b[3];
  return r;
}

DI unsigned pkmax0(unsigned t) {  // packed f16 relu
  unsigned r;
  asm("v_pk_max_f16 %0, %1, 0" : "=v"(r) : "v"(t));
  return r;
}

// ---- lane-group swaps for the LN cross-group reduction only ----
DI void swap16(unsigned& a, unsigned& b) {
#if __has_builtin(__builtin_amdgcn_permlane16_swap)
  auto r = __builtin_amdgcn_permlane16_swap(a, b, false, false);
  a = r[0]; b = r[1];
#else
  unsigned ax = (unsigned)__shfl_xor((int)a, 16);
  unsigned bx = (unsigned)__shfl_xor((int)b, 16);
  bool odd = (threadIdx.x & 16) != 0;
  unsigned na = odd ? bx : a;
  unsigned nb = odd ? b : ax;
  a = na; b = nb;
#endif
}
DI void swap32(unsigned& a, unsigned& b) {
#if __has_builtin(__builtin_amdgcn_permlane32_swap)
  auto r = __builtin_amdgcn_permlane32_swap(a, b, false, false);
  a = r[0]; b = r[1];
#else
  unsigned ax = (unsigned)__shfl_xor((int)a, 32);
  unsigned bx = (unsigned)__shfl_xor((int)b, 32);
  bool hi = (threadIdx.x & 32) != 0;
  unsigned na = hi ? bx : a;
  unsigned nb = hi ? b : ax;
  a = na; b = nb;
#endif
}

DI float reduce4(float x) {  // sum across the 4 g-groups (same l15)
  unsigned a = __builtin_bit_cast(unsigned, x), b = a;
  swap16(a, b);
  float x1 = __builtin_bit_cast(float, a) + __builtin_bit_cast(float, b);
  unsigned c = __builtin_bit_cast(unsigned, x1), d = c;
  swap32(c, d);
  return __builtin_bit_cast(float, c) + __builtin_bit_cast(float, d);
}

union BU {  // u[0..3] = b0 frag (k 0..31), u[4..7] = b1 frag (k 32..63)
  unsigned u[8];
  struct { f16x8 b0, b1; } f;
};

// D-layout acc -> B-operand; with pi-permuted weights the order is identity.
template <bool RELU>
DI void packacc(const f32x4 (&acc)[4], BU& o) {
#pragma unroll
  for (int tp = 0; tp < 4; ++tp) {
    unsigned p0 = pkrtz(acc[tp][0], acc[tp][1]);
    unsigned p1 = pkrtz(acc[tp][2], acc[tp][3]);
    if (RELU) { p0 = pkmax0(p0); p1 = pkmax0(p1); }
    o.u[2 * tp + 0] = p0;
    o.u[2 * tp + 1] = p1;
  }
}

struct WFrag { f16x8 f[4][2]; };  // [tp][khalf] A-frags (pi-permuted K-cols)

// pi: slot (s,g,j) <- feature 32s + 4g + j (j<4) / 32s+16+4g+(j-4) (j>=4).
DI WFrag loadW(const float* W, int l15, int g) {  // f32 row-major 64x64
  WFrag w;
#pragma unroll
  for (int tp = 0; tp < 4; ++tp)
#pragma unroll
    for (int s = 0; s < 2; ++s) {
      const float* p = W + (16 * tp + l15) * 64 + 32 * s + 4 * g;
      w.f[tp][s] = cvt8h(*(const f32x4*)p, *(const f32x4*)(p + 16));
    }
  return w;
}

DI f32x4 mfma(f16x8 a, f16x8 b, f32x4 c) {
  return __builtin_amdgcn_mfma_f32_16x16x32_f16(a, b, c, 0, 0, 0);
}

// Dual-chain LayerNorm: stats per chain, shared gamma/beta loads (global/L2).
DI void lnorm2(const f32x4 (&aA)[4], const f32x4 (&aB)[4], const float* gb,
               int g, f32x4 (&hA)[4], f32x4 (&hB)[4]) {
  float sA = 0.f, qA = 0.f, sB = 0.f, qB = 0.f;
#pragma unroll
  for (int tp = 0; tp < 4; ++tp)
#pragma unroll
    for (int r = 0; r < 4; ++r) {
      float xa = aA[tp][r]; sA += xa; qA = fmaf(xa, xa, qA);
      float xb = aB[tp][r]; sB += xb; qB = fmaf(xb, xb, qB);
    }
  sA = reduce4(sA); qA = reduce4(qA);
  sB = reduce4(sB); qB = reduce4(qB);
  float mA = sA * 0.015625f, mB = sB * 0.015625f;
  float rA = rsq(fmaf(qA, 0.015625f, -mA * mA) + EPS);
  float rB = rsq(fmaf(qB, 0.015625f, -mB * mB) + EPS);
  float uA = -mA * rA, uB = -mB * rB;
  const f32x4* gv = (const f32x4*)gb;
#pragma unroll
  for (int tp = 0; tp < 4; ++tp) {
    f32x4 gg = gv[4 * tp + g];
    f32x4 bb = gv[16 + 4 * tp + g];
#pragma unroll
    for (int r = 0; r < 4; ++r) {
      hA[tp][r] = fmaf(fmaf(aA[tp][r], rA, uA), gg[r], bb[r]);
      hB[tp][r] = fmaf(fmaf(aB[tp][r], rB, uB), gg[r], bb[r]);
    }
  }
}

// One transformer layer, both chains, all weights in registers.
DI void do_layer(f32x4 (&hA)[4], f32x4 (&hB)[4], BU& bA, BU& bB,
                 const WFrag& wvo, const WFrag& w1, const WFrag& w2,
                 const float* prm, int g) {
  asm("" : "+r"(prm));  // keep param loads in-loop (no giant LICM hoist)
  const f32x4* pv = (const f32x4*)prm;
  f32x4 aA[4], aB[4];
  // ---- P1: a = h + W_vo@h + b_vo ; h = LN1(a) ----
#pragma unroll
  for (int tp = 0; tp < 4; ++tp) {
    aA[tp] = mfma(wvo.f[tp][1], bA.f.b1, mfma(wvo.f[tp][0], bA.f.b0, hA[tp]));
    aB[tp] = mfma(wvo.f[tp][1], bB.f.b1, mfma(wvo.f[tp][0], bB.f.b0, hB[tp]));
    f32x4 bv = pv[4 * tp + g];
    aA[tp] += bv; aB[tp] += bv;
  }
  lnorm2(aA, aB, prm + 192, g, hA, hB);
  packacc<false>(hA, bA); packacc<false>(hB, bB);
  // ---- P2: t = relu(W1@h + b1) ----
#pragma unroll
  for (int tp = 0; tp < 4; ++tp) {
    f32x4 cin = pv[16 + 4 * tp + g];
    aA[tp] = mfma(w1.f[tp][1], bA.f.b1, mfma(w1.f[tp][0], bA.f.b0, cin));
    aB[tp] = mfma(w1.f[tp][1], bB.f.b1, mfma(w1.f[tp][0], bB.f.b0, cin));
  }
  packacc<true>(aA, bA); packacc<true>(aB, bB);
  // ---- P3: a = h + W2@t + b2 ; h = LN2(a) ----
#pragma unroll
  for (int tp = 0; tp < 4; ++tp) {
    aA[tp] = mfma(w2.f[tp][1], bA.f.b1, mfma(w2.f[tp][0], bA.f.b0, hA[tp]));
    aB[tp] = mfma(w2.f[tp][1], bB.f.b1, mfma(w2.f[tp][0], bB.f.b0, hB[tp]));
    f32x4 bv = pv[32 + 4 * tp + g];
    aA[tp] += bv; aB[tp] += bv;
  }
  lnorm2(aA, aB, prm + 320, g, hA, hB);
  packacc<false>(hA, bA); packacc<false>(hB, bB);
}

// ---------- precompute: W_vo, b_vo, and packed param table ----------
// ws layout (floats): [0..4095] W_vo l0, [4096..8191] W_vo l1,
// [8192..] params: per layer 448 = [bvo|b1|b2|g1|be1|g2|be2] x 64.
__global__ __launch_bounds__(256) void precompute_kernel(
    const float* __restrict__ Wqkv, const float* __restrict__ bqkv,
    const float* __restrict__ Wo, const float* __restrict__ bo,
    const float* __restrict__ b1, const float* __restrict__ b2,
    const float* __restrict__ ln1_g, const float* __restrict__ ln1_b,
    const float* __restrict__ ln2_g, const float* __restrict__ ln2_b,
    float* __restrict__ ws) {
  __shared__ float wv[4096];
  __shared__ float wo[4096];
  const int l = blockIdx.x;
  const float* Wv  = Wqkv + l * (192 * 64) + 128 * 64;
  const float* WoL = Wo + l * 4096;
  for (int e = threadIdx.x; e < 4096; e += 256) { wv[e] = Wv[e]; wo[e] = WoL[e]; }
  __syncthreads();
  float* wvo = ws + l * 4096;
  const int i = threadIdx.x >> 2, j0 = (threadIdx.x & 3) * 16;
  float acc[16];
#pragma unroll
  for (int jj = 0; jj < 16; ++jj) acc[jj] = 0.f;
  for (int k = 0; k < 64; ++k) {
    float a = wo[i * 64 + k];
#pragma unroll
    for (int jj = 0; jj < 16; ++jj) acc[jj] = fmaf(a, wv[k * 64 + j0 + jj], acc[jj]);
  }
#pragma unroll
  for (int jj = 0; jj < 16; ++jj) wvo[i * 64 + j0 + jj] = acc[jj];
  float* prm = ws + 2 * 4096 + l * 448;
  if (threadIdx.x < 64) {
    const int i2 = threadIdx.x;
    const float* bv = bqkv + l * 192 + 128;
    float s = bo[l * 64 + i2];
    for (int k = 0; k < 64; ++k) s = fmaf(wo[i2 * 64 + k], bv[k], s);
    prm[i2]       = s;                  // bvo
    prm[64 + i2]  = b1[l * 64 + i2];
    prm[128 + i2] = b2[l * 64 + i2];
    prm[192 + i2] = ln1_g[l * 64 + i2];
    prm[256 + i2] = ln1_b[l * 64 + i2];
    prm[320 + i2] = ln2_g[l * 64 + i2];
    prm[384 + i2] = ln2_b[l * 64 + i2];
  }
}

// ---------- main fused kernel ----------
// (256,1): compiler VGPR budget 256. Live set ~240 (6 WFrags = 192 + state).
// HW: <=256 VGPR still schedules 2 waves/SIMD (pool 512). No LDS at all.
__global__ __launch_bounds__(256, 1) void trm13_kernel(
    const float* __restrict__ x, const float* __restrict__ input_w,
    const float* __restrict__ input_b, const float* __restrict__ W1,
    const float* __restrict__ W2, const float* __restrict__ out_w,
    const float* __restrict__ out_b, const float* __restrict__ ws,
    float* __restrict__ out) {
  const int tid = threadIdx.x;
  const int w = tid >> 6, lane = tid & 63;
  const int l15 = lane & 15, g = lane >> 4;
  const int row0 = blockIdx.x * 128 + w * 32;  // chain A rows row0.., B +16

  // ---- ALL weights as register fragments (pi-permuted K-cols) ----
  WFrag wvo0 = loadW(ws, l15, g);
  WFrag wvo1 = loadW(ws + 4096, l15, g);
  WFrag w1r0 = loadW(W1, l15, g);
  WFrag w1r1 = loadW(W1 + 4096, l15, g);
  WFrag w2r0 = loadW(W2, l15, g);
  WFrag w2r1 = loadW(W2 + 4096, l15, g);

  const float* prm0 = ws + 2 * 4096;
  const float* prm1 = ws + 2 * 4096 + 448;

  // ---- input projection: h = x @ input_w^T + input_b (K=200) ----
  f32x4 hA[4], hB[4];
#pragma unroll
  for (int tp = 0; tp < 4; ++tp) {
    f32x4 ib = *(const f32x4*)(input_b + 16 * tp + 4 * g);
    hA[tp] = ib; hB[tp] = ib;
  }
  {
    const float* xA = x + (size_t)(row0 + l15) * 200;
    const float* xB = xA + 16 * 200;
    const f32x4 zero = {0.f, 0.f, 0.f, 0.f};
    for (int s7 = 0; s7 < 7; ++s7) {
      int kb = 32 * s7 + 8 * g;
      bool v0 = kb < 200;
      f32x4 xa0 = v0 ? *(const f32x4*)(xA + kb) : zero;
      f32x4 xa1 = v0 ? *(const f32x4*)(xA + kb + 4) : zero;
      f32x4 xb0 = v0 ? *(const f32x4*)(xB + kb) : zero;
      f32x4 xb1 = v0 ? *(const f32x4*)(xB + kb + 4) : zero;
      f16x8 bfA = cvt8h(xa0, xa1);
      f16x8 bfB = cvt8h(xb0, xb1);
#pragma unroll
      for (int tp = 0; tp < 4; ++tp) {
        const float* wr = input_w + (16 * tp + l15) * 200;
        f32x4 wa = v0 ? *(const f32x4*)(wr + kb) : zero;
        f32x4 wb = v0 ? *(const f32x4*)(wr + kb + 4) : zero;
        f16x8 af = cvt8h(wa, wb);
        hA[tp] = mfma(af, bfA, hA[tp]);
        hB[tp] = mfma(af, bfB, hB[tp]);
      }
    }
  }
  BU bA, bB;
  packacc<false>(hA, bA); packacc<false>(hB, bB);

  // ---- recurrence: 16 steps x 2 layers; zero LDS, zero barriers ----
#pragma unroll 1
  for (int step = 0; step < 16; ++step) {
    do_layer(hA, hB, bA, bB, wvo0, w1r0, w2r0, prm0, g);
    do_layer(hA, hB, bA, bB, wvo1, w1r1, w2r1, prm1, g);
  }

  // ---- out = h . out_w + out_b ----
  float pA = 0.f, pB = 0.f;
#pragma unroll
  for (int tp = 0; tp < 4; ++tp) {
    f32x4 ow = *(const f32x4*)(out_w + 16 * tp + 4 * g);
#pragma unroll
    for (int r = 0; r < 4; ++r) {
      pA = fmaf(hA[tp][r], ow[r], pA);
      pB = fmaf(hB[tp][r], ow[r], pB);
    }
  }
  pA += __shfl_xor(pA, 16); pA += __shfl_xor(pA, 32);
  pB += __shfl_xor(pB, 16); pB += __shfl_xor(pB, 32);
  if (lane < 16) {
    float ob = out_b[0];
    out[row0 + l15]      = pA + ob;
    out[row0 + 16 + l15] = pB + ob;
  }
}

}  // namespace

extern "C" void kernel_launch(void* const* d_in, const int* in_sizes, int n_in,
                              void* d_out, int out_size, void* d_ws, size_t ws_size,
                              hipStream_t stream) {
  const float* x       = (const float*)d_in[0];
  const float* input_w = (const float*)d_in[1];
  const float* input_b = (const float*)d_in[2];
  const float* Wqkv    = (const float*)d_in[3];
  const float* bqkv    = (const float*)d_in[4];
  const float* Wo      = (const float*)d_in[5];
  const float* bo      = (const float*)d_in[6];
  const float* ln1_g   = (const float*)d_in[7];
  const float* ln1_b   = (const float*)d_in[8];
  const float* W1      = (const float*)d_in[9];
  const float* b1      = (const float*)d_in[10];
  const float* W2      = (const float*)d_in[11];
  const float* b2      = (const float*)d_in[12];
  const float* ln2_g   = (const float*)d_in[13];
  const float* ln2_b   = (const float*)d_in[14];
  const float* out_w   = (const float*)d_in[15];
  const float* out_b   = (const float*)d_in[16];
  float* out = (float*)d_out;
  float* ws  = (float*)d_ws;

  hipLaunchKernelGGL(precompute_kernel, dim3(2), dim3(256), 0, stream,
                     Wqkv, bqkv, Wo, bo, b1, b2, ln1_g, ln1_b, ln2_g, ln2_b, ws);
  hipLaunchKernelGGL(trm13_kernel, dim3(512), dim3(256), 0, stream,
                     x, input_w, input_b, W1, W2, out_w, out_b, ws, out);
}

// Round 14
// 107.437 us; speedup vs baseline: 1.3741x; 1.3741x over previous
//
#include <hip/hip_runtime.h>

// TinyRecursiveModel fused kernel, v14 == v12 (verified 107us champion).
// Dual 16-row chains/wave, pi-permuted weights (no lane exchange), W1/W2 in
// padded LDS, W_vo in VGPRs, params via global/L2, pkrtz pack, v_rsq LN.
// v13 (all-weights-in-VGPR, 236 regs) dropped to 1 wave/SIMD -> reverted.

using f16x8 = __attribute__((ext_vector_type(8))) _Float16;
using f32x4 = __attribute__((ext_vector_type(4))) float;

#define DI __device__ __forceinline__

namespace {

constexpr int RS = 144;   // LDS row stride bytes for weight mats (128B + 16B pad)
constexpr float EPS = 1e-5f;

DI float rsq(float x) {
#if __has_builtin(__builtin_amdgcn_rsqf)
  return __builtin_amdgcn_rsqf(x);
#else
  float r;
  asm("v_rsq_f32 %0, %1" : "=v"(r) : "v"(x));
  return r;
#endif
}

DI unsigned pkrtz(float a, float b) {  // two f32 -> packed f16 pair (RTZ)
#if __has_builtin(__builtin_amdgcn_cvt_pkrtz)
  return __builtin_bit_cast(unsigned, __builtin_amdgcn_cvt_pkrtz(a, b));
#else
  unsigned r;
  asm("v_cvt_pkrtz_f16_f32 %0, %1, %2" : "=v"(r) : "v"(a), "v"(b));
  return r;
#endif
}

DI f16x8 cvt8h(f32x4 a, f32x4 b) {  // RNE (weights/input staging)
  f16x8 r;
  r[0] = (_Float16)a[0]; r[1] = (_Float16)a[1];
  r[2] = (_Float16)a[2]; r[3] = (_Float16)a[3];
  r[4] = (_Float16)b[0]; r[5] = (_Float16)b[1];
  r[6] = (_Float16)b[2]; r[7] = (_Float16)b[3];
  return r;
}

DI unsigned pkmax0(unsigned t) {  // packed f16 relu
  unsigned r;
  asm("v_pk_max_f16 %0, %1, 0" : "=v"(r) : "v"(t));
  return r;
}

// ---- lane-group swaps for the LN cross-group reduction only ----
DI void swap16(unsigned& a, unsigned& b) {
#if __has_builtin(__builtin_amdgcn_permlane16_swap)
  auto r = __builtin_amdgcn_permlane16_swap(a, b, false, false);
  a = r[0]; b = r[1];
#else
  unsigned ax = (unsigned)__shfl_xor((int)a, 16);
  unsigned bx = (unsigned)__shfl_xor((int)b, 16);
  bool odd = (threadIdx.x & 16) != 0;
  unsigned na = odd ? bx : a;
  unsigned nb = odd ? b : ax;
  a = na; b = nb;
#endif
}
DI void swap32(unsigned& a, unsigned& b) {
#if __has_builtin(__builtin_amdgcn_permlane32_swap)
  auto r = __builtin_amdgcn_permlane32_swap(a, b, false, false);
  a = r[0]; b = r[1];
#else
  unsigned ax = (unsigned)__shfl_xor((int)a, 32);
  unsigned bx = (unsigned)__shfl_xor((int)b, 32);
  bool hi = (threadIdx.x & 32) != 0;
  unsigned na = hi ? bx : a;
  unsigned nb = hi ? b : ax;
  a = na; b = nb;
#endif
}

DI float reduce4(float x) {  // sum across the 4 g-groups (same l15)
  unsigned a = __builtin_bit_cast(unsigned, x), b = a;
  swap16(a, b);
  float x1 = __builtin_bit_cast(float, a) + __builtin_bit_cast(float, b);
  unsigned c = __builtin_bit_cast(unsigned, x1), d = c;
  swap32(c, d);
  return __builtin_bit_cast(float, c) + __builtin_bit_cast(float, d);
}

union BU {  // u[0..3] = b0 frag (k 0..31), u[4..7] = b1 frag (k 32..63)
  unsigned u[8];
  struct { f16x8 b0, b1; } f;
};

// D-layout acc -> B-operand; with pi-permuted weights the order is identity.
template <bool RELU>
DI void packacc(const f32x4 (&acc)[4], BU& o) {
#pragma unroll
  for (int tp = 0; tp < 4; ++tp) {
    unsigned p0 = pkrtz(acc[tp][0], acc[tp][1]);
    unsigned p1 = pkrtz(acc[tp][2], acc[tp][3]);
    if (RELU) { p0 = pkmax0(p0); p1 = pkmax0(p1); }
    o.u[2 * tp + 0] = p0;
    o.u[2 * tp + 1] = p1;
  }
}

struct WFrag { f16x8 f[4][2]; };  // [tp][khalf] A-frags (pi-permuted K-cols)

// pi: slot (s,g,j) <- feature 32s + 4g + j (j<4) / 32s+16+4g+(j-4) (j>=4).
DI WFrag loadW(const float* W, int l15, int g) {  // f32 row-major 64x64
  WFrag w;
#pragma unroll
  for (int tp = 0; tp < 4; ++tp)
#pragma unroll
    for (int s = 0; s < 2; ++s) {
      const float* p = W + (16 * tp + l15) * 64 + 32 * s + 4 * g;
      w.f[tp][s] = cvt8h(*(const f32x4*)p, *(const f32x4*)(p + 16));
    }
  return w;
}

DI f32x4 mfma(f16x8 a, f16x8 b, f32x4 c) {
  return __builtin_amdgcn_mfma_f32_16x16x32_f16(a, b, c, 0, 0, 0);
}

// Dual-chain LayerNorm: stats per chain, shared gamma/beta loads (global/L2).
DI void lnorm2(const f32x4 (&aA)[4], const f32x4 (&aB)[4], const float* gb,
               int g, f32x4 (&hA)[4], f32x4 (&hB)[4]) {
  float sA = 0.f, qA = 0.f, sB = 0.f, qB = 0.f;
#pragma unroll
  for (int tp = 0; tp < 4; ++tp)
#pragma unroll
    for (int r = 0; r < 4; ++r) {
      float xa = aA[tp][r]; sA += xa; qA = fmaf(xa, xa, qA);
      float xb = aB[tp][r]; sB += xb; qB = fmaf(xb, xb, qB);
    }
  sA = reduce4(sA); qA = reduce4(qA);
  sB = reduce4(sB); qB = reduce4(qB);
  float mA = sA * 0.015625f, mB = sB * 0.015625f;
  float rA = rsq(fmaf(qA, 0.015625f, -mA * mA) + EPS);
  float rB = rsq(fmaf(qB, 0.015625f, -mB * mB) + EPS);
  float uA = -mA * rA, uB = -mB * rB;
  const f32x4* gv = (const f32x4*)gb;
#pragma unroll
  for (int tp = 0; tp < 4; ++tp) {
    f32x4 gg = gv[4 * tp + g];
    f32x4 bb = gv[16 + 4 * tp + g];
#pragma unroll
    for (int r = 0; r < 4; ++r) {
      hA[tp][r] = fmaf(fmaf(aA[tp][r], rA, uA), gg[r], bb[r]);
      hB[tp][r] = fmaf(fmaf(aB[tp][r], rB, uB), gg[r], bb[r]);
    }
  }
}

struct alignas(16) Smem {
  char mats[4][64 * RS];  // W1 l0, W1 l1, W2 l0, W2 l1 (f16, padded, pi-cols)
};

// One transformer layer, both chains. prm: [bvo|b1|b2|g1|be1|g2|be2] x 64.
DI void do_layer(f32x4 (&hA)[4], f32x4 (&hB)[4], BU& bA, BU& bB,
                 const WFrag& wvo, const char* w1b, const char* w2b,
                 const float* prm, int g) {
  asm("" : "+r"(prm));  // keep param loads in-loop (no giant LICM hoist)
  const f32x4* pv = (const f32x4*)prm;
  f32x4 aA[4], aB[4];
  // ---- P1: a = h + W_vo@h + b_vo ; h = LN1(a) ----
#pragma unroll
  for (int tp = 0; tp < 4; ++tp) {
    aA[tp] = mfma(wvo.f[tp][1], bA.f.b1, mfma(wvo.f[tp][0], bA.f.b0, hA[tp]));
    aB[tp] = mfma(wvo.f[tp][1], bB.f.b1, mfma(wvo.f[tp][0], bB.f.b0, hB[tp]));
    f32x4 bv = pv[4 * tp + g];
    aA[tp] += bv; aB[tp] += bv;
  }
  lnorm2(aA, aB, prm + 192, g, hA, hB);
  packacc<false>(hA, bA); packacc<false>(hB, bB);
  // ---- P2: t = relu(W1@h + b1) ----
#pragma unroll
  for (int tp = 0; tp < 4; ++tp) {
    f16x8 a0 = *(const f16x8*)(w1b + tp * 16 * RS);
    f16x8 a1 = *(const f16x8*)(w1b + tp * 16 * RS + 64);
    f32x4 cin = pv[16 + 4 * tp + g];
    aA[tp] = mfma(a1, bA.f.b1, mfma(a0, bA.f.b0, cin));
    aB[tp] = mfma(a1, bB.f.b1, mfma(a0, bB.f.b0, cin));
  }
  packacc<true>(aA, bA); packacc<true>(aB, bB);
  // ---- P3: a = h + W2@t + b2 ; h = LN2(a) ----
#pragma unroll
  for (int tp = 0; tp < 4; ++tp) {
    f16x8 a0 = *(const f16x8*)(w2b + tp * 16 * RS);
    f16x8 a1 = *(const f16x8*)(w2b + tp * 16 * RS + 64);
    aA[tp] = mfma(a1, bA.f.b1, mfma(a0, bA.f.b0, hA[tp]));
    aB[tp] = mfma(a1, bB.f.b1, mfma(a0, bB.f.b0, hB[tp]));
    f32x4 bv = pv[32 + 4 * tp + g];
    aA[tp] += bv; aB[tp] += bv;
  }
  lnorm2(aA, aB, prm + 320, g, hA, hB);
  packacc<false>(hA, bA); packacc<false>(hB, bB);
}

// ---------- precompute: W_vo, b_vo, and packed param table ----------
// ws layout (floats): [0..4095] W_vo l0, [4096..8191] W_vo l1,
// [8192..] params: per layer 448 = [bvo|b1|b2|g1|be1|g2|be2] x 64.
__global__ __launch_bounds__(256) void precompute_kernel(
    const float* __restrict__ Wqkv, const float* __restrict__ bqkv,
    const float* __restrict__ Wo, const float* __restrict__ bo,
    const float* __restrict__ b1, const float* __restrict__ b2,
    const float* __restrict__ ln1_g, const float* __restrict__ ln1_b,
    const float* __restrict__ ln2_g, const float* __restrict__ ln2_b,
    float* __restrict__ ws) {
  __shared__ float wv[4096];
  __shared__ float wo[4096];
  const int l = blockIdx.x;
  const float* Wv  = Wqkv + l * (192 * 64) + 128 * 64;
  const float* WoL = Wo + l * 4096;
  for (int e = threadIdx.x; e < 4096; e += 256) { wv[e] = Wv[e]; wo[e] = WoL[e]; }
  __syncthreads();
  float* wvo = ws + l * 4096;
  const int i = threadIdx.x >> 2, j0 = (threadIdx.x & 3) * 16;
  float acc[16];
#pragma unroll
  for (int jj = 0; jj < 16; ++jj) acc[jj] = 0.f;
  for (int k = 0; k < 64; ++k) {
    float a = wo[i * 64 + k];
#pragma unroll
    for (int jj = 0; jj < 16; ++jj) acc[jj] = fmaf(a, wv[k * 64 + j0 + jj], acc[jj]);
  }
#pragma unroll
  for (int jj = 0; jj < 16; ++jj) wvo[i * 64 + j0 + jj] = acc[jj];
  float* prm = ws + 2 * 4096 + l * 448;
  if (threadIdx.x < 64) {
    const int i2 = threadIdx.x;
    const float* bv = bqkv + l * 192 + 128;
    float s = bo[l * 64 + i2];
    for (int k = 0; k < 64; ++k) s = fmaf(wo[i2 * 64 + k], bv[k], s);
    prm[i2]       = s;                  // bvo
    prm[64 + i2]  = b1[l * 64 + i2];
    prm[128 + i2] = b2[l * 64 + i2];
    prm[192 + i2] = ln1_g[l * 64 + i2];
    prm[256 + i2] = ln1_b[l * 64 + i2];
    prm[320 + i2] = ln2_g[l * 64 + i2];
    prm[384 + i2] = ln2_b[l * 64 + i2];
  }
}

// ---------- main fused kernel ----------
__global__ __launch_bounds__(256, 2) void trm14_kernel(
    const float* __restrict__ x, const float* __restrict__ input_w,
    const float* __restrict__ input_b, const float* __restrict__ W1,
    const float* __restrict__ W2, const float* __restrict__ out_w,
    const float* __restrict__ out_b, const float* __restrict__ ws,
    float* __restrict__ out) {
  __shared__ Smem sm;
  const int tid = threadIdx.x;
  const int w = tid >> 6, lane = tid & 63;
  const int l15 = lane & 15, g = lane >> 4;
  const int row0 = blockIdx.x * 128 + w * 32;  // chain A rows row0.., B +16

  // ---- stage W1/W2 (both layers) as f16, pi-permuted K-cols, padded ----
  {
    const float* srcs[4] = {W1, W1 + 4096, W2, W2 + 4096};
#pragma unroll
    for (int m = 0; m < 4; ++m) {
      char* dst = sm.mats[m];
      const float* src = srcs[m];
      for (int e = tid; e < 512; e += 256) {
        int row = e >> 3, q = e & 7, s = q >> 2, gq = q & 3;
        const float* p = src + row * 64 + 32 * s + 4 * gq;
        *(f16x8*)(dst + row * RS + 64 * s + 16 * gq) =
            cvt8h(*(const f32x4*)p, *(const f32x4*)(p + 16));
      }
    }
  }

  // ---- W_vo(l0,l1) fragments in registers (pi-permuted) ----
  WFrag wvo0 = loadW(ws, l15, g);
  WFrag wvo1 = loadW(ws + 4096, l15, g);

  const char* w1b0 = sm.mats[0] + l15 * RS + 16 * g;
  const char* w1b1 = sm.mats[1] + l15 * RS + 16 * g;
  const char* w2b0 = sm.mats[2] + l15 * RS + 16 * g;
  const char* w2b1 = sm.mats[3] + l15 * RS + 16 * g;
  const float* prm0 = ws + 2 * 4096;
  const float* prm1 = ws + 2 * 4096 + 448;

  // ---- input projection: h = x @ input_w^T + input_b (K=200) ----
  f32x4 hA[4], hB[4];
#pragma unroll
  for (int tp = 0; tp < 4; ++tp) {
    f32x4 ib = *(const f32x4*)(input_b + 16 * tp + 4 * g);
    hA[tp] = ib; hB[tp] = ib;
  }
  {
    const float* xA = x + (size_t)(row0 + l15) * 200;
    const float* xB = xA + 16 * 200;
    const f32x4 zero = {0.f, 0.f, 0.f, 0.f};
    for (int s7 = 0; s7 < 7; ++s7) {
      int kb = 32 * s7 + 8 * g;
      bool v0 = kb < 200;
      f32x4 xa0 = v0 ? *(const f32x4*)(xA + kb) : zero;
      f32x4 xa1 = v0 ? *(const f32x4*)(xA + kb + 4) : zero;
      f32x4 xb0 = v0 ? *(const f32x4*)(xB + kb) : zero;
      f32x4 xb1 = v0 ? *(const f32x4*)(xB + kb + 4) : zero;
      f16x8 bfA = cvt8h(xa0, xa1);
      f16x8 bfB = cvt8h(xb0, xb1);
#pragma unroll
      for (int tp = 0; tp < 4; ++tp) {
        const float* wr = input_w + (16 * tp + l15) * 200;
        f32x4 wa = v0 ? *(const f32x4*)(wr + kb) : zero;
        f32x4 wb = v0 ? *(const f32x4*)(wr + kb + 4) : zero;
        f16x8 af = cvt8h(wa, wb);
        hA[tp] = mfma(af, bfA, hA[tp]);
        hB[tp] = mfma(af, bfB, hB[tp]);
      }
    }
  }
  BU bA, bB;
  packacc<false>(hA, bA); packacc<false>(hB, bB);
  __syncthreads();  // weight mats staged; the only block barrier

  // ---- recurrence: 16 steps x 2 layers; no LDS writes, no fences ----
#pragma unroll 1
  for (int step = 0; step < 16; ++step) {
    do_layer(hA, hB, bA, bB, wvo0, w1b0, w2b0, prm0, g);
    do_layer(hA, hB, bA, bB, wvo1, w1b1, w2b1, prm1, g);
  }

  // ---- out = h . out_w + out_b ----
  float pA = 0.f, pB = 0.f;
#pragma unroll
  for (int tp = 0; tp < 4; ++tp) {
    f32x4 ow = *(const f32x4*)(out_w + 16 * tp + 4 * g);
#pragma unroll
    for (int r = 0; r < 4; ++r) {
      pA = fmaf(hA[tp][r], ow[r], pA);
      pB = fmaf(hB[tp][r], ow[r], pB);
    }
  }
  pA += __shfl_xor(pA, 16); pA += __shfl_xor(pA, 32);
  pB += __shfl_xor(pB, 16); pB += __shfl_xor(pB, 32);
  if (lane < 16) {
    float ob = out_b[0];
    out[row0 + l15]      = pA + ob;
    out[row0 + 16 + l15] = pB + ob;
  }
}

}  // namespace

extern "C" void kernel_launch(void* const* d_in, const int* in_sizes, int n_in,
                              void* d_out, int out_size, void* d_ws, size_t ws_size,
                              hipStream_t stream) {
  const float* x       = (const float*)d_in[0];
  const float* input_w = (const float*)d_in[1];
  const float* input_b = (const float*)d_in[2];
  const float* Wqkv    = (const float*)d_in[3];
  const float* bqkv    = (const float*)d_in[4];
  const float* Wo      = (const float*)d_in[5];
  const float* bo      = (const float*)d_in[6];
  const float* ln1_g   = (const float*)d_in[7];
  const float* ln1_b   = (const float*)d_in[8];
  const float* W1      = (const float*)d_in[9];
  const float* b1      = (const float*)d_in[10];
  const float* W2      = (const float*)d_in[11];
  const float* b2      = (const float*)d_in[12];
  const float* ln2_g   = (const float*)d_in[13];
  const float* ln2_b   = (const float*)d_in[14];
  const float* out_w   = (const float*)d_in[15];
  const float* out_b   = (const float*)d_in[16];
  float* out = (float*)d_out;
  float* ws  = (float*)d_ws;

  hipLaunchKernelGGL(precompute_kernel, dim3(2), dim3(256), 0, stream,
                     Wqkv, bqkv, Wo, bo, b1, b2, ln1_g, ln1_b, ln2_g, ln2_b, ws);
  hipLaunchKernelGGL(trm14_kernel, dim3(512), dim3(256), 0, stream,
                     x, input_w, input_b, W1, W2, out_w, out_b, ws, out);
}